// Round 7
// baseline (640.096 us; speedup 1.0000x reference)
//
#include <hip/hip_runtime.h>

// TAGConv x2 on MI355X — round 6: degree-grouped hop scheduling (counting sort -> vseg
// table in d_out scratch, kills 1.6x wave divergence), 4-edge pass1. bf16 storage, f32 accum.

namespace {
constexpr int NN = 100000;
constexpr int NE = 1600000;
constexpr int TPB = 256;

typedef __attribute__((ext_vector_type(8))) short short8v;
typedef __attribute__((ext_vector_type(4))) float float4v;

__device__ __forceinline__ float bflo(unsigned p) { return __uint_as_float(p << 16); }
__device__ __forceinline__ float bfhi(unsigned p) { return __uint_as_float(p & 0xffff0000u); }
__device__ __forceinline__ unsigned f2bf(float x) {
  unsigned u = __float_as_uint(x);
  return (u + 0x7fffu + ((u >> 16) & 1u)) >> 16;  // RNE
}
__device__ __forceinline__ unsigned pack2(float lo, float hi) {
  return f2bf(lo) | (f2bf(hi) << 16);
}

// ---------- preprocessing ----------
__global__ void pass1_kernel(const int* __restrict__ col, const float* __restrict__ w,
                             unsigned long long* __restrict__ acc64, int* __restrict__ rank) {
  int base = blockIdx.x * (TPB * 4) + threadIdx.x;
#pragma unroll
  for (int i = 0; i < 4; ++i) {
    int e = base + i * TPB;
    if (e < NE) {
      int c = col[e];
      unsigned long long v =
          (1ULL << 40) | (unsigned long long)__float2uint_rn(w[e] * 16777216.0f);
      unsigned long long old = atomicAdd(&acc64[c], v);
      rank[e] = (int)(old >> 40);
    }
  }
}

__global__ void dis_kernel(const unsigned long long* __restrict__ acc64,
                           float* __restrict__ dis) {
  int n = blockIdx.x * TPB + threadIdx.x;
  if (n >= NN) return;
  unsigned long long u = acc64[n] & ((1ULL << 40) - 1);
  float d = (float)u * (1.0f / 16777216.0f);
  dis[n] = d > 0.f ? rsqrtf(d) : 0.f;
}

__global__ void scan1_kernel(const unsigned long long* __restrict__ acc64,
                             int* __restrict__ excl, int* __restrict__ btot) {
  __shared__ int sh[1024];
  int i = blockIdx.x * 1024 + threadIdx.x;
  int v = (i < NN) ? (int)(acc64[i] >> 40) : 0;
  sh[threadIdx.x] = v;
  __syncthreads();
  for (int ofs = 1; ofs < 1024; ofs <<= 1) {
    int t = (threadIdx.x >= ofs) ? sh[threadIdx.x - ofs] : 0;
    __syncthreads();
    sh[threadIdx.x] += t;
    __syncthreads();
  }
  if (i < NN) excl[i] = sh[threadIdx.x] - v;
  if (threadIdx.x == 1023) btot[blockIdx.x] = sh[1023];
}

__global__ void scan2_kernel(int* __restrict__ btot, int nb) {
  __shared__ int sh[128];
  int t = threadIdx.x;
  if (t < nb) sh[t] = btot[t];
  __syncthreads();
  if (t == 0) {
    int run = 0;
    for (int b = 0; b < nb; ++b) { int x = sh[b]; sh[b] = run; run += x; }
  }
  __syncthreads();
  if (t < nb) btot[t] = sh[t];
}

__global__ void scan3_kernel(const int* __restrict__ excl, const int* __restrict__ btot,
                             int* __restrict__ rowptr) {
  int i = blockIdx.x * TPB + threadIdx.x;
  if (i < NN) rowptr[i] = excl[i] + btot[i >> 10];
  if (i == NN) rowptr[NN] = NE;
}

__global__ void fill2_kernel(const int* __restrict__ row, const int* __restrict__ col,
                             const float* __restrict__ w, const float* __restrict__ dis,
                             const int* __restrict__ rank, const int* __restrict__ rowptr,
                             int2* __restrict__ edges) {
  int e = blockIdx.x * TPB + threadIdx.x;
  if (e >= NE) return;
  int r = row[e], c = col[e];
  float nw = dis[r] * w[e] * dis[c];
  edges[rowptr[c] + rank[e]] = make_int2(r, __float_as_int(nw));
}

// ---------- degree counting sort -> vseg[(e0,e1,n)] grouped by (descending) degree ----------
__global__ void dhist_kernel(const int* __restrict__ rowptr, int* __restrict__ ghist) {
  __shared__ int lh[128];
  if (threadIdx.x < 128) lh[threadIdx.x] = 0;
  __syncthreads();
  int n = blockIdx.x * TPB + threadIdx.x;
  if (n < NN) {
    int d = rowptr[n + 1] - rowptr[n];
    atomicAdd(&lh[min(d, 127)], 1);
  }
  __syncthreads();
  if (threadIdx.x < 128 && lh[threadIdx.x]) atomicAdd(&ghist[threadIdx.x], lh[threadIdx.x]);
}

__global__ void dscan_kernel(const int* __restrict__ ghist, int* __restrict__ gcur) {
  if (threadIdx.x == 0) {
    int run = 0;
    for (int b = 127; b >= 0; --b) { gcur[b] = run; run += ghist[b]; }  // descending degree
  }
}

__global__ void dscatter_kernel(const int* __restrict__ rowptr, int* __restrict__ gcur,
                                int4* __restrict__ vseg) {
  __shared__ int lh[128], lbase[128], lcur[128];
  if (threadIdx.x < 128) { lh[threadIdx.x] = 0; lcur[threadIdx.x] = 0; }
  __syncthreads();
  int n = blockIdx.x * TPB + threadIdx.x;
  int e0 = 0, e1 = 0, bin = 0;
  if (n < NN) {
    e0 = rowptr[n]; e1 = rowptr[n + 1];
    bin = min(e1 - e0, 127);
    atomicAdd(&lh[bin], 1);
  }
  __syncthreads();
  if (threadIdx.x < 128)
    lbase[threadIdx.x] = lh[threadIdx.x] ? atomicAdd(&gcur[threadIdx.x], lh[threadIdx.x]) : 0;
  __syncthreads();
  if (n < NN) {
    int off = atomicAdd(&lcur[bin], 1);
    vseg[lbase[bin] + off] = make_int4(e0, e1, n, 0);
  }
}

// W0 [384][128] f32 -> fragment-ordered bf16
__global__ void wfrag0_kernel(const float* __restrict__ W0, short* __restrict__ F) {
  int t = blockIdx.x * TPB + threadIdx.x;
  if (t >= 12 * 8 * 64) return;
  int l = t & 63, nt = (t >> 6) & 7, s = t >> 9;
  int c = nt * 16 + (l & 15);
  int kb = s * 32 + (l >> 4) * 8;
  short8v v;
#pragma unroll
  for (int j = 0; j < 8; ++j) v[j] = (short)f2bf(W0[(kb + j) * 128 + c]);
  *(short8v*)(F + (size_t)t * 8) = v;
}

// W1 [6][128][64] viewed as B[f][J]=W1[J>>6][f][J&63]
__global__ void wfrag1_kernel(const float* __restrict__ W1, short* __restrict__ F) {
  int t = blockIdx.x * TPB + threadIdx.x;
  if (t >= 4 * 24 * 64) return;
  int l = t & 63, nt = (t >> 6) % 24, s = t / (64 * 24);
  int J = nt * 16 + (l & 15);
  int fb = s * 32 + (l >> 4) * 8;
  const float* Wb = W1 + (size_t)(J >> 6) * (128 * 64) + (J & 63);
  short8v v;
#pragma unroll
  for (int j = 0; j < 8; ++j) v[j] = (short)f2bf(Wb[(size_t)(fb + j) * 64]);
  *(short8v*)(F + (size_t)t * 8) = v;
}

// x f32 [N][64] -> Hcat slice 0
__global__ void convx_kernel(const float* __restrict__ x, unsigned* __restrict__ hcat) {
  unsigned idx = blockIdx.x * (unsigned)TPB + threadIdx.x;
  if (idx >= (unsigned)NN * 32u) return;
  unsigned n = idx >> 5, p = idx & 31u;
  float2 v = *(const float2*)(x + (size_t)n * 64 + p * 2);
  hcat[(size_t)n * 192 + p] = pack2(v.x, v.y);
}

// ---------- hop: 8 lanes/node, 16B per lane, 4-edge unrolled dwordx4 gathers ----------
__device__ __forceinline__ void fma8(float* a, uint4 p, float w) {
  a[0] = fmaf(bflo(p.x), w, a[0]); a[1] = fmaf(bfhi(p.x), w, a[1]);
  a[2] = fmaf(bflo(p.y), w, a[2]); a[3] = fmaf(bfhi(p.y), w, a[3]);
  a[4] = fmaf(bflo(p.z), w, a[4]); a[5] = fmaf(bfhi(p.z), w, a[5]);
  a[6] = fmaf(bflo(p.w), w, a[6]); a[7] = fmaf(bfhi(p.w), w, a[7]);
}

template <bool VSEG, bool YADD, bool FINAL>
__global__ void hop_kernel(const unsigned short* __restrict__ src, int sstride,
                           const int2* __restrict__ edges, const int* __restrict__ rowptr,
                           const int4* __restrict__ vseg,
                           const unsigned short* __restrict__ y,
                           unsigned short* __restrict__ dst, int dstride,
                           const float* __restrict__ bias, float* __restrict__ outf) {
  unsigned vn = blockIdx.x * 32u + (threadIdx.x >> 3);
  unsigned lane = threadIdx.x & 7u;
  unsigned f0 = lane * 8u;
  int e, e1;
  unsigned n;
  if (VSEG) {
    int4 s = vseg[vn];
    e = s.x; e1 = s.y; n = (unsigned)s.z;
  } else {
    n = vn;
    e = rowptr[n]; e1 = rowptr[n + 1];
  }
  float a[8] = {};
  for (; e + 3 < e1; e += 4) {
    int2 d0 = edges[e], d1 = edges[e + 1], d2 = edges[e + 2], d3 = edges[e + 3];
    uint4 p0 = *(const uint4*)(src + (size_t)(unsigned)d0.x * sstride + f0);
    uint4 p1 = *(const uint4*)(src + (size_t)(unsigned)d1.x * sstride + f0);
    uint4 p2 = *(const uint4*)(src + (size_t)(unsigned)d2.x * sstride + f0);
    uint4 p3 = *(const uint4*)(src + (size_t)(unsigned)d3.x * sstride + f0);
    fma8(a, p0, __int_as_float(d0.y));
    fma8(a, p1, __int_as_float(d1.y));
    fma8(a, p2, __int_as_float(d2.y));
    fma8(a, p3, __int_as_float(d3.y));
  }
  if (e + 1 < e1) {
    int2 d0 = edges[e], d1 = edges[e + 1];
    uint4 p0 = *(const uint4*)(src + (size_t)(unsigned)d0.x * sstride + f0);
    uint4 p1 = *(const uint4*)(src + (size_t)(unsigned)d1.x * sstride + f0);
    fma8(a, p0, __int_as_float(d0.y));
    fma8(a, p1, __int_as_float(d1.y));
    e += 2;
  }
  if (e < e1) {
    int2 d0 = edges[e];
    uint4 p0 = *(const uint4*)(src + (size_t)(unsigned)d0.x * sstride + f0);
    fma8(a, p0, __int_as_float(d0.y));
  }
  if (YADD) {
    uint4 yv = *(const uint4*)(y + (size_t)n * 384 + f0);
    a[0] += bflo(yv.x); a[1] += bfhi(yv.x);
    a[2] += bflo(yv.y); a[3] += bfhi(yv.y);
    a[4] += bflo(yv.z); a[5] += bfhi(yv.z);
    a[6] += bflo(yv.w); a[7] += bfhi(yv.w);
  }
  if (FINAL) {
    const float4* bp = (const float4*)(bias + f0);
    float4 bv0 = bp[0], bv1 = bp[1];
    float4 o0, o1;
    o0.x = a[0] + bv0.x; o0.y = a[1] + bv0.y; o0.z = a[2] + bv0.z; o0.w = a[3] + bv0.w;
    o1.x = a[4] + bv1.x; o1.y = a[5] + bv1.y; o1.z = a[6] + bv1.z; o1.w = a[7] + bv1.w;
    o0.x = o0.x >= 0.f ? o0.x : 0.01f * o0.x; o0.y = o0.y >= 0.f ? o0.y : 0.01f * o0.y;
    o0.z = o0.z >= 0.f ? o0.z : 0.01f * o0.z; o0.w = o0.w >= 0.f ? o0.w : 0.01f * o0.w;
    o1.x = o1.x >= 0.f ? o1.x : 0.01f * o1.x; o1.y = o1.y >= 0.f ? o1.y : 0.01f * o1.y;
    o1.z = o1.z >= 0.f ? o1.z : 0.01f * o1.z; o1.w = o1.w >= 0.f ? o1.w : 0.01f * o1.w;
    float4* op = (float4*)(outf + (size_t)n * 64 + f0);
    op[0] = o0; op[1] = o1;
  } else {
    uint4 st;
    st.x = pack2(a[0], a[1]); st.y = pack2(a[2], a[3]);
    st.z = pack2(a[4], a[5]); st.w = pack2(a[6], a[7]);
    *(uint4*)(dst + (size_t)n * dstride + f0) = st;
  }
}

// ---------- MFMA GEMM layer 0 ----------
__global__ void gemm_l0(const unsigned short* __restrict__ A, const short* __restrict__ W0f,
                        const float* __restrict__ bias, unsigned short* __restrict__ H1) {
  int wave = threadIdx.x >> 6, lane = threadIdx.x & 63;
  int lrow = lane & 15, lk = lane >> 4;
  unsigned r0 = blockIdx.x * 64u + (unsigned)wave * 16u;
  unsigned arow = r0 + (unsigned)lrow;
  if (arow >= NN) arow = NN - 1;
  const short8v* Ab = (const short8v*)(A + (size_t)arow * 384 + (unsigned)lk * 8);
  const short8v* Bb = (const short8v*)W0f + lane;
  float4v acc[8] = {};
#pragma unroll
  for (int s = 0; s < 12; ++s) {
    short8v a = Ab[s * 4];
#pragma unroll
    for (int nt = 0; nt < 8; ++nt) {
      short8v b = Bb[(s * 8 + nt) * 64];
      acc[nt] = __builtin_amdgcn_mfma_f32_16x16x32_bf16(a, b, acc[nt], 0, 0, 0);
    }
  }
#pragma unroll
  for (int nt = 0; nt < 8; ++nt) {
    int c = nt * 16 + lrow;
    float bv = bias[c];
#pragma unroll
    for (int r = 0; r < 4; ++r) {
      unsigned n = r0 + (unsigned)(lk * 4 + r);
      if (n < NN) {
        float v = acc[nt][r] + bv;
        v = v >= 0.f ? v : 0.01f * v;
        H1[(size_t)n * 128 + c] = (unsigned short)f2bf(v);
      }
    }
  }
}

// ---------- MFMA GEMM layer 1 (col-split over gridDim.y=3) ----------
__global__ void gemm_l1(const unsigned short* __restrict__ A, const short* __restrict__ W1f,
                        unsigned short* __restrict__ Y) {
  int wave = threadIdx.x >> 6, lane = threadIdx.x & 63;
  int lrow = lane & 15, lk = lane >> 4;
  int yb = blockIdx.y * 8;
  unsigned r0 = blockIdx.x * 64u + (unsigned)wave * 16u;
  unsigned arow = r0 + (unsigned)lrow;
  if (arow >= NN) arow = NN - 1;
  const short8v* Ab = (const short8v*)(A + (size_t)arow * 128 + (unsigned)lk * 8);
  const short8v* Bb = (const short8v*)W1f + lane;
  float4v acc[8] = {};
#pragma unroll
  for (int s = 0; s < 4; ++s) {
    short8v a = Ab[s * 4];
#pragma unroll
    for (int nt = 0; nt < 8; ++nt) {
      short8v b = Bb[(s * 24 + yb + nt) * 64];
      acc[nt] = __builtin_amdgcn_mfma_f32_16x16x32_bf16(a, b, acc[nt], 0, 0, 0);
    }
  }
#pragma unroll
  for (int nt = 0; nt < 8; ++nt) {
    int c = (yb + nt) * 16 + lrow;
#pragma unroll
    for (int r = 0; r < 4; ++r) {
      unsigned n = r0 + (unsigned)(lk * 4 + r);
      if (n < NN) Y[(size_t)n * 384 + c] = (unsigned short)f2bf(acc[nt][r]);
    }
  }
}

}  // namespace

extern "C" void kernel_launch(void* const* d_in, const int* in_sizes, int n_in,
                              void* d_out, int out_size, void* d_ws, size_t ws_size,
                              hipStream_t stream) {
  const float* x  = (const float*)d_in[0];
  const int*   ei = (const int*)d_in[1];
  const float* ew = (const float*)d_in[2];
  const float* W0 = (const float*)d_in[3];
  const float* b0 = (const float*)d_in[4];
  const float* W1 = (const float*)d_in[5];
  const float* b1 = (const float*)d_in[6];
  float* out = (float*)d_out;
  const int* row = ei;
  const int* col = ei + NE;

  constexpr size_t OFF_DIS    = 0;
  constexpr size_t OFF_ROWPTR = 100352;
  constexpr size_t OFF_BTOT   = OFF_ROWPTR + 100352;
  constexpr size_t OFF_EDGES  = OFF_BTOT + 128;
  constexpr size_t OFF_HCAT   = OFF_EDGES + 2 * (size_t)NE;
  constexpr size_t OFF_H1     = OFF_HCAT + (size_t)NN * 384 / 2;
  constexpr size_t WS_WORDS   = OFF_H1 + (size_t)NN * 128 / 2;
  if (ws_size < WS_WORDS * sizeof(float)) return;

  float* ws = (float*)d_ws;
  float* dis    = ws + OFF_DIS;
  int*   rowptr = (int*)(ws + OFF_ROWPTR);
  int*   btot   = (int*)(ws + OFF_BTOT);
  int2*  edges  = (int2*)(ws + OFF_EDGES);
  unsigned short* Hcat = (unsigned short*)(ws + OFF_HCAT);
  unsigned short* H1   = (unsigned short*)(ws + OFF_H1);
  short* W0f = (short*)(ws + OFF_DIS);
  short* W1f = (short*)(ws + OFF_DIS + 24576);
  unsigned long long* acc64 = (unsigned long long*)(ws + OFF_H1);
  int* excl = (int*)(ws + OFF_H1 + 200704);
  int* rank = (int*)Hcat;
  unsigned short* z0 = H1;
  unsigned short* z1 = H1 + (size_t)NN * 64;
  // d_out as scratch until the final hop: vseg[NN] int4 | ghist[128] | gcur[128]
  int4* vseg = (int4*)d_out;                 // 400000 ints
  int* ghist = (int*)d_out + 400000;
  int* gcur  = ghist + 128;

  hipMemsetAsync(acc64, 0, NN * sizeof(unsigned long long), stream);
  hipMemsetAsync(ghist, 0, 256 * sizeof(int), stream);
  pass1_kernel<<<(NE + TPB * 4 - 1) / (TPB * 4), TPB, 0, stream>>>(col, ew, acc64, rank);
  dis_kernel<<<(NN + TPB - 1) / TPB, TPB, 0, stream>>>(acc64, dis);
  scan1_kernel<<<98, 1024, 0, stream>>>(acc64, excl, btot);
  scan2_kernel<<<1, 128, 0, stream>>>(btot, 98);
  scan3_kernel<<<(NN + TPB) / TPB, TPB, 0, stream>>>(excl, btot, rowptr);
  fill2_kernel<<<(NE + TPB - 1) / TPB, TPB, 0, stream>>>(row, col, ew, dis, rank, rowptr, edges);
  dhist_kernel<<<(NN + TPB - 1) / TPB, TPB, 0, stream>>>(rowptr, ghist);
  dscan_kernel<<<1, 64, 0, stream>>>(ghist, gcur);
  dscatter_kernel<<<(NN + TPB - 1) / TPB, TPB, 0, stream>>>(rowptr, gcur, vseg);
  wfrag0_kernel<<<24, TPB, 0, stream>>>(W0, W0f);
  wfrag1_kernel<<<24, TPB, 0, stream>>>(W1, W1f);

  // layer 0
  convx_kernel<<<NN * 32 / TPB, TPB, 0, stream>>>(x, (unsigned*)Hcat);
  for (int k = 1; k <= 5; ++k) {
    hop_kernel<true, false, false><<<NN / 32, TPB, 0, stream>>>(
        Hcat + (k - 1) * 64, 384, edges, rowptr, vseg, nullptr,
        Hcat + k * 64, 384, nullptr, nullptr);
  }
  gemm_l0<<<(NN + 63) / 64, TPB, 0, stream>>>(Hcat, W0f, b0, H1);

  // layer 1: Y then Horner
  gemm_l1<<<dim3((NN + 63) / 64, 3), TPB, 0, stream>>>(H1, W1f, Hcat);
  const unsigned short* Y = Hcat;
  hop_kernel<true, true, false><<<NN / 32, TPB, 0, stream>>>(
      Y + 5 * 64, 384, edges, rowptr, vseg, Y + 4 * 64, z0, 64, nullptr, nullptr);
  hop_kernel<true, true, false><<<NN / 32, TPB, 0, stream>>>(
      z0, 64, edges, rowptr, vseg, Y + 3 * 64, z1, 64, nullptr, nullptr);
  hop_kernel<true, true, false><<<NN / 32, TPB, 0, stream>>>(
      z1, 64, edges, rowptr, vseg, Y + 2 * 64, z0, 64, nullptr, nullptr);
  hop_kernel<true, true, false><<<NN / 32, TPB, 0, stream>>>(
      z0, 64, edges, rowptr, vseg, Y + 1 * 64, z1, 64, nullptr, nullptr);
  // final hop writes d_out -> must not rely on vseg (it lives in d_out): unsorted path
  hop_kernel<false, true, true><<<NN / 32, TPB, 0, stream>>>(
      z1, 64, edges, rowptr, nullptr, Y + 0 * 64, nullptr, 0, b1, out);
}

// Round 9
// 628.078 us; speedup vs baseline: 1.0191x; 1.0191x over previous
//
#include <hip/hip_runtime.h>

// TAGConv x2 on MI355X — round 8 (resubmit of round 7; prior bench was an infra timeout):
// revert vseg (divergence-sort lost to locality), pass1 with 32-bit packed atomics
// (count<<21 | fix13(w)). bf16 storage, f32 accum.

namespace {
constexpr int NN = 100000;
constexpr int NE = 1600000;
constexpr int TPB = 256;

typedef __attribute__((ext_vector_type(8))) short short8v;
typedef __attribute__((ext_vector_type(4))) float float4v;

__device__ __forceinline__ float bflo(unsigned p) { return __uint_as_float(p << 16); }
__device__ __forceinline__ float bfhi(unsigned p) { return __uint_as_float(p & 0xffff0000u); }
__device__ __forceinline__ unsigned f2bf(float x) {
  unsigned u = __float_as_uint(x);
  return (u + 0x7fffu + ((u >> 16) & 1u)) >> 16;  // RNE
}
__device__ __forceinline__ unsigned pack2(float lo, float hi) {
  return f2bf(lo) | (f2bf(hi) << 16);
}

// ---------- preprocessing ----------
// 32-bit packed atomic per edge: acc32[c] += (1<<21) | fix13(w).
// old>>21 = this edge's rank within its destination; low 21 bits accumulate deg
// in 2^-13 fixed point (safe while deg < 256; Poisson(16) max ~60).
__global__ void pass1_kernel(const int* __restrict__ col, const float* __restrict__ w,
                             unsigned* __restrict__ acc32, int* __restrict__ rank) {
  int e = blockIdx.x * TPB + threadIdx.x;
  if (e >= NE) return;
  int c = col[e];
  unsigned v = (1u << 21) | (unsigned)__float2uint_rn(w[e] * 8192.0f);
  unsigned old = atomicAdd(&acc32[c], v);
  rank[e] = (int)(old >> 21);
}

__global__ void dis_kernel(const unsigned* __restrict__ acc32, float* __restrict__ dis) {
  int n = blockIdx.x * TPB + threadIdx.x;
  if (n >= NN) return;
  float d = (float)(acc32[n] & 0x1FFFFFu) * (1.0f / 8192.0f);
  dis[n] = d > 0.f ? rsqrtf(d) : 0.f;
}

__global__ void scan1_kernel(const unsigned* __restrict__ acc32, int* __restrict__ excl,
                             int* __restrict__ btot) {
  __shared__ int sh[1024];
  int i = blockIdx.x * 1024 + threadIdx.x;
  int v = (i < NN) ? (int)(acc32[i] >> 21) : 0;
  sh[threadIdx.x] = v;
  __syncthreads();
  for (int ofs = 1; ofs < 1024; ofs <<= 1) {
    int t = (threadIdx.x >= ofs) ? sh[threadIdx.x - ofs] : 0;
    __syncthreads();
    sh[threadIdx.x] += t;
    __syncthreads();
  }
  if (i < NN) excl[i] = sh[threadIdx.x] - v;
  if (threadIdx.x == 1023) btot[blockIdx.x] = sh[1023];
}

__global__ void scan2_kernel(int* __restrict__ btot, int nb) {
  __shared__ int sh[128];
  int t = threadIdx.x;
  if (t < nb) sh[t] = btot[t];
  __syncthreads();
  if (t == 0) {
    int run = 0;
    for (int b = 0; b < nb; ++b) { int x = sh[b]; sh[b] = run; run += x; }
  }
  __syncthreads();
  if (t < nb) btot[t] = sh[t];
}

__global__ void scan3_kernel(const int* __restrict__ excl, const int* __restrict__ btot,
                             int* __restrict__ rowptr) {
  int i = blockIdx.x * TPB + threadIdx.x;
  if (i < NN) rowptr[i] = excl[i] + btot[i >> 10];
  if (i == NN) rowptr[NN] = NE;
}

__global__ void fill2_kernel(const int* __restrict__ row, const int* __restrict__ col,
                             const float* __restrict__ w, const float* __restrict__ dis,
                             const int* __restrict__ rank, const int* __restrict__ rowptr,
                             int2* __restrict__ edges) {
  int e = blockIdx.x * TPB + threadIdx.x;
  if (e >= NE) return;
  int r = row[e], c = col[e];
  float nw = dis[r] * w[e] * dis[c];
  edges[rowptr[c] + rank[e]] = make_int2(r, __float_as_int(nw));
}

// W0 [384][128] f32 -> fragment-ordered bf16
__global__ void wfrag0_kernel(const float* __restrict__ W0, short* __restrict__ F) {
  int t = blockIdx.x * TPB + threadIdx.x;
  if (t >= 12 * 8 * 64) return;
  int l = t & 63, nt = (t >> 6) & 7, s = t >> 9;
  int c = nt * 16 + (l & 15);
  int kb = s * 32 + (l >> 4) * 8;
  short8v v;
#pragma unroll
  for (int j = 0; j < 8; ++j) v[j] = (short)f2bf(W0[(kb + j) * 128 + c]);
  *(short8v*)(F + (size_t)t * 8) = v;
}

// W1 [6][128][64] viewed as B[f][J]=W1[J>>6][f][J&63]
__global__ void wfrag1_kernel(const float* __restrict__ W1, short* __restrict__ F) {
  int t = blockIdx.x * TPB + threadIdx.x;
  if (t >= 4 * 24 * 64) return;
  int l = t & 63, nt = (t >> 6) % 24, s = t / (64 * 24);
  int J = nt * 16 + (l & 15);
  int fb = s * 32 + (l >> 4) * 8;
  const float* Wb = W1 + (size_t)(J >> 6) * (128 * 64) + (J & 63);
  short8v v;
#pragma unroll
  for (int j = 0; j < 8; ++j) v[j] = (short)f2bf(Wb[(size_t)(fb + j) * 64]);
  *(short8v*)(F + (size_t)t * 8) = v;
}

// x f32 [N][64] -> Hcat slice 0
__global__ void convx_kernel(const float* __restrict__ x, unsigned* __restrict__ hcat) {
  unsigned idx = blockIdx.x * (unsigned)TPB + threadIdx.x;
  if (idx >= (unsigned)NN * 32u) return;
  unsigned n = idx >> 5, p = idx & 31u;
  float2 v = *(const float2*)(x + (size_t)n * 64 + p * 2);
  hcat[(size_t)n * 192 + p] = pack2(v.x, v.y);
}

// ---------- hop: 8 lanes/node, 16B per lane, 4-edge unrolled dwordx4 gathers ----------
__device__ __forceinline__ void fma8(float* a, uint4 p, float w) {
  a[0] = fmaf(bflo(p.x), w, a[0]); a[1] = fmaf(bfhi(p.x), w, a[1]);
  a[2] = fmaf(bflo(p.y), w, a[2]); a[3] = fmaf(bfhi(p.y), w, a[3]);
  a[4] = fmaf(bflo(p.z), w, a[4]); a[5] = fmaf(bfhi(p.z), w, a[5]);
  a[6] = fmaf(bflo(p.w), w, a[6]); a[7] = fmaf(bfhi(p.w), w, a[7]);
}

template <bool YADD, bool FINAL>
__global__ void hop_kernel(const unsigned short* __restrict__ src, int sstride,
                           const int2* __restrict__ edges, const int* __restrict__ rowptr,
                           const unsigned short* __restrict__ y,
                           unsigned short* __restrict__ dst, int dstride,
                           const float* __restrict__ bias, float* __restrict__ outf) {
  unsigned n = blockIdx.x * 32u + (threadIdx.x >> 3);
  unsigned lane = threadIdx.x & 7u;
  unsigned f0 = lane * 8u;
  int e = rowptr[n], e1 = rowptr[n + 1];
  float a[8] = {};
  for (; e + 3 < e1; e += 4) {
    int2 d0 = edges[e], d1 = edges[e + 1], d2 = edges[e + 2], d3 = edges[e + 3];
    uint4 p0 = *(const uint4*)(src + (size_t)(unsigned)d0.x * sstride + f0);
    uint4 p1 = *(const uint4*)(src + (size_t)(unsigned)d1.x * sstride + f0);
    uint4 p2 = *(const uint4*)(src + (size_t)(unsigned)d2.x * sstride + f0);
    uint4 p3 = *(const uint4*)(src + (size_t)(unsigned)d3.x * sstride + f0);
    fma8(a, p0, __int_as_float(d0.y));
    fma8(a, p1, __int_as_float(d1.y));
    fma8(a, p2, __int_as_float(d2.y));
    fma8(a, p3, __int_as_float(d3.y));
  }
  if (e + 1 < e1) {
    int2 d0 = edges[e], d1 = edges[e + 1];
    uint4 p0 = *(const uint4*)(src + (size_t)(unsigned)d0.x * sstride + f0);
    uint4 p1 = *(const uint4*)(src + (size_t)(unsigned)d1.x * sstride + f0);
    fma8(a, p0, __int_as_float(d0.y));
    fma8(a, p1, __int_as_float(d1.y));
    e += 2;
  }
  if (e < e1) {
    int2 d0 = edges[e];
    uint4 p0 = *(const uint4*)(src + (size_t)(unsigned)d0.x * sstride + f0);
    fma8(a, p0, __int_as_float(d0.y));
  }
  if (YADD) {
    uint4 yv = *(const uint4*)(y + (size_t)n * 384 + f0);
    a[0] += bflo(yv.x); a[1] += bfhi(yv.x);
    a[2] += bflo(yv.y); a[3] += bfhi(yv.y);
    a[4] += bflo(yv.z); a[5] += bfhi(yv.z);
    a[6] += bflo(yv.w); a[7] += bfhi(yv.w);
  }
  if (FINAL) {
    const float4* bp = (const float4*)(bias + f0);
    float4 bv0 = bp[0], bv1 = bp[1];
    float4 o0, o1;
    o0.x = a[0] + bv0.x; o0.y = a[1] + bv0.y; o0.z = a[2] + bv0.z; o0.w = a[3] + bv0.w;
    o1.x = a[4] + bv1.x; o1.y = a[5] + bv1.y; o1.z = a[6] + bv1.z; o1.w = a[7] + bv1.w;
    o0.x = o0.x >= 0.f ? o0.x : 0.01f * o0.x; o0.y = o0.y >= 0.f ? o0.y : 0.01f * o0.y;
    o0.z = o0.z >= 0.f ? o0.z : 0.01f * o0.z; o0.w = o0.w >= 0.f ? o0.w : 0.01f * o0.w;
    o1.x = o1.x >= 0.f ? o1.x : 0.01f * o1.x; o1.y = o1.y >= 0.f ? o1.y : 0.01f * o1.y;
    o1.z = o1.z >= 0.f ? o1.z : 0.01f * o1.z; o1.w = o1.w >= 0.f ? o1.w : 0.01f * o1.w;
    float4* op = (float4*)(outf + (size_t)n * 64 + f0);
    op[0] = o0; op[1] = o1;
  } else {
    uint4 st;
    st.x = pack2(a[0], a[1]); st.y = pack2(a[2], a[3]);
    st.z = pack2(a[4], a[5]); st.w = pack2(a[6], a[7]);
    *(uint4*)(dst + (size_t)n * dstride + f0) = st;
  }
}

// ---------- MFMA GEMM layer 0 ----------
__global__ void gemm_l0(const unsigned short* __restrict__ A, const short* __restrict__ W0f,
                        const float* __restrict__ bias, unsigned short* __restrict__ H1) {
  int wave = threadIdx.x >> 6, lane = threadIdx.x & 63;
  int lrow = lane & 15, lk = lane >> 4;
  unsigned r0 = blockIdx.x * 64u + (unsigned)wave * 16u;
  unsigned arow = r0 + (unsigned)lrow;
  if (arow >= NN) arow = NN - 1;
  const short8v* Ab = (const short8v*)(A + (size_t)arow * 384 + (unsigned)lk * 8);
  const short8v* Bb = (const short8v*)W0f + lane;
  float4v acc[8] = {};
#pragma unroll
  for (int s = 0; s < 12; ++s) {
    short8v a = Ab[s * 4];
#pragma unroll
    for (int nt = 0; nt < 8; ++nt) {
      short8v b = Bb[(s * 8 + nt) * 64];
      acc[nt] = __builtin_amdgcn_mfma_f32_16x16x32_bf16(a, b, acc[nt], 0, 0, 0);
    }
  }
#pragma unroll
  for (int nt = 0; nt < 8; ++nt) {
    int c = nt * 16 + lrow;
    float bv = bias[c];
#pragma unroll
    for (int r = 0; r < 4; ++r) {
      unsigned n = r0 + (unsigned)(lk * 4 + r);
      if (n < NN) {
        float v = acc[nt][r] + bv;
        v = v >= 0.f ? v : 0.01f * v;
        H1[(size_t)n * 128 + c] = (unsigned short)f2bf(v);
      }
    }
  }
}

// ---------- MFMA GEMM layer 1 (col-split over gridDim.y=3) ----------
__global__ void gemm_l1(const unsigned short* __restrict__ A, const short* __restrict__ W1f,
                        unsigned short* __restrict__ Y) {
  int wave = threadIdx.x >> 6, lane = threadIdx.x & 63;
  int lrow = lane & 15, lk = lane >> 4;
  int yb = blockIdx.y * 8;
  unsigned r0 = blockIdx.x * 64u + (unsigned)wave * 16u;
  unsigned arow = r0 + (unsigned)lrow;
  if (arow >= NN) arow = NN - 1;
  const short8v* Ab = (const short8v*)(A + (size_t)arow * 128 + (unsigned)lk * 8);
  const short8v* Bb = (const short8v*)W1f + lane;
  float4v acc[8] = {};
#pragma unroll
  for (int s = 0; s < 4; ++s) {
    short8v a = Ab[s * 4];
#pragma unroll
    for (int nt = 0; nt < 8; ++nt) {
      short8v b = Bb[(s * 24 + yb + nt) * 64];
      acc[nt] = __builtin_amdgcn_mfma_f32_16x16x32_bf16(a, b, acc[nt], 0, 0, 0);
    }
  }
#pragma unroll
  for (int nt = 0; nt < 8; ++nt) {
    int c = (yb + nt) * 16 + lrow;
#pragma unroll
    for (int r = 0; r < 4; ++r) {
      unsigned n = r0 + (unsigned)(lk * 4 + r);
      if (n < NN) Y[(size_t)n * 384 + c] = (unsigned short)f2bf(acc[nt][r]);
    }
  }
}

}  // namespace

extern "C" void kernel_launch(void* const* d_in, const int* in_sizes, int n_in,
                              void* d_out, int out_size, void* d_ws, size_t ws_size,
                              hipStream_t stream) {
  const float* x  = (const float*)d_in[0];
  const int*   ei = (const int*)d_in[1];
  const float* ew = (const float*)d_in[2];
  const float* W0 = (const float*)d_in[3];
  const float* b0 = (const float*)d_in[4];
  const float* W1 = (const float*)d_in[5];
  const float* b1 = (const float*)d_in[6];
  float* out = (float*)d_out;
  const int* row = ei;
  const int* col = ei + NE;

  constexpr size_t OFF_DIS    = 0;
  constexpr size_t OFF_ROWPTR = 100352;
  constexpr size_t OFF_BTOT   = OFF_ROWPTR + 100352;
  constexpr size_t OFF_EDGES  = OFF_BTOT + 128;
  constexpr size_t OFF_HCAT   = OFF_EDGES + 2 * (size_t)NE;
  constexpr size_t OFF_H1     = OFF_HCAT + (size_t)NN * 384 / 2;
  constexpr size_t WS_WORDS   = OFF_H1 + (size_t)NN * 128 / 2;
  if (ws_size < WS_WORDS * sizeof(float)) return;

  float* ws = (float*)d_ws;
  float* dis    = ws + OFF_DIS;
  int*   rowptr = (int*)(ws + OFF_ROWPTR);
  int*   btot   = (int*)(ws + OFF_BTOT);
  int2*  edges  = (int2*)(ws + OFF_EDGES);
  unsigned short* Hcat = (unsigned short*)(ws + OFF_HCAT);
  unsigned short* H1   = (unsigned short*)(ws + OFF_H1);
  short* W0f = (short*)(ws + OFF_DIS);
  short* W1f = (short*)(ws + OFF_DIS + 24576);
  // preprocessing transients: acc32+excl in H1 region, rank in Hcat region (dead later)
  unsigned* acc32 = (unsigned*)(ws + OFF_H1);
  int* excl = (int*)(ws + OFF_H1 + 100352);
  int* rank = (int*)Hcat;
  unsigned short* z0 = H1;
  unsigned short* z1 = H1 + (size_t)NN * 64;

  hipMemsetAsync(acc32, 0, NN * sizeof(unsigned), stream);
  pass1_kernel<<<(NE + TPB - 1) / TPB, TPB, 0, stream>>>(col, ew, acc32, rank);
  dis_kernel<<<(NN + TPB - 1) / TPB, TPB, 0, stream>>>(acc32, dis);
  scan1_kernel<<<98, 1024, 0, stream>>>(acc32, excl, btot);
  scan2_kernel<<<1, 128, 0, stream>>>(btot, 98);
  scan3_kernel<<<(NN + TPB) / TPB, TPB, 0, stream>>>(excl, btot, rowptr);
  fill2_kernel<<<(NE + TPB - 1) / TPB, TPB, 0, stream>>>(row, col, ew, dis, rank, rowptr, edges);
  wfrag0_kernel<<<24, TPB, 0, stream>>>(W0, W0f);
  wfrag1_kernel<<<24, TPB, 0, stream>>>(W1, W1f);

  // layer 0
  convx_kernel<<<NN * 32 / TPB, TPB, 0, stream>>>(x, (unsigned*)Hcat);
  for (int k = 1; k <= 5; ++k) {
    hop_kernel<false, false><<<NN / 32, TPB, 0, stream>>>(
        Hcat + (k - 1) * 64, 384, edges, rowptr, nullptr,
        Hcat + k * 64, 384, nullptr, nullptr);
  }
  gemm_l0<<<(NN + 63) / 64, TPB, 0, stream>>>(Hcat, W0f, b0, H1);

  // layer 1: Y then Horner
  gemm_l1<<<dim3((NN + 63) / 64, 3), TPB, 0, stream>>>(H1, W1f, Hcat);
  const unsigned short* Y = Hcat;
  hop_kernel<true, false><<<NN / 32, TPB, 0, stream>>>(
      Y + 5 * 64, 384, edges, rowptr, Y + 4 * 64, z0, 64, nullptr, nullptr);
  hop_kernel<true, false><<<NN / 32, TPB, 0, stream>>>(
      z0, 64, edges, rowptr, Y + 3 * 64, z1, 64, nullptr, nullptr);
  hop_kernel<true, false><<<NN / 32, TPB, 0, stream>>>(
      z1, 64, edges, rowptr, Y + 2 * 64, z0, 64, nullptr, nullptr);
  hop_kernel<true, false><<<NN / 32, TPB, 0, stream>>>(
      z0, 64, edges, rowptr, Y + 1 * 64, z1, 64, nullptr, nullptr);
  hop_kernel<true, true><<<NN / 32, TPB, 0, stream>>>(
      z1, 64, edges, rowptr, Y + 0 * 64, nullptr, 0, b1, out);
}